// Round 15
// baseline (733.206 us; speedup 1.0000x reference)
//
#include <hip/hip_runtime.h>
#include <hip/hip_bf16.h>

// ---------------------------------------------------------------------------
// MatGCN: 4-layer GCN (D=128) + LN + residual + mean-pool + linear head.
// R13 (third submit; two prior benches lost to container-level infra failure —
// same signature as R9, which passed unchanged on its third attempt):
// k_matmul drops the W LDS tile (B-frags loaded per-lane from global;
// Wt = 32 KB, L1-resident) -> LDS 69.6->34.8 KB, 2->4 blocks/CU.
// k_node gather widened to 8-edge batches. Build phase unchanged from R12.
// ---------------------------------------------------------------------------

typedef __hip_bfloat162 bf2;
typedef __attribute__((ext_vector_type(8))) short short8;
typedef __attribute__((ext_vector_type(4))) float f32x4;

#define NGROUPS 16          // node-range groups (nn = ceil(n/16) = 6250)
#define NSLICES 128         // edge slices; grid = NSLICES*NGROUPS = 2048
#define NN_MAX 6400         // >= ceil(100000/16); 25.6 KB LDS

// Pass A: per-(slice,group) node histogram. LDS atomics only; int4 dst loads.
__global__ __launch_bounds__(256) void k_bhist(const int* __restrict__ dst,
                                               int* __restrict__ bh, int n, int E) {
    __shared__ int h[NN_MAX];
    const int b = blockIdx.x, g = b & (NGROUPS - 1);
    const int nn = (n + NGROUPS - 1) / NGROUPS;
    const int lo = g * nn;
    const int hi = min(n, lo + nn);
    for (int i = threadIdx.x; i < nn; i += 256) h[i] = 0;
    __syncthreads();
    const int per = (((E + NSLICES - 1) / NSLICES) + 3) & ~3;   // mult of 4
    const int e0 = (b >> 4) * per, e1 = min(E, e0 + per);
    for (int base = e0 + threadIdx.x * 4; base < e1; base += 1024) {
        if (base + 4 <= e1) {
            int4 d4 = *(const int4*)(dst + base);
            if (d4.x >= lo && d4.x < hi) atomicAdd(&h[d4.x - lo], 1);
            if (d4.y >= lo && d4.y < hi) atomicAdd(&h[d4.y - lo], 1);
            if (d4.z >= lo && d4.z < hi) atomicAdd(&h[d4.z - lo], 1);
            if (d4.w >= lo && d4.w < hi) atomicAdd(&h[d4.w - lo], 1);
        } else {
            for (int j = 0; j < 4; j++) {
                int ee = base + j;
                if (ee < e1) {
                    int d = dst[ee];
                    if (d >= lo && d < hi) atomicAdd(&h[d - lo], 1);
                }
            }
        }
    }
    __syncthreads();
    int* out = bh + (size_t)b * nn;
    for (int i = threadIdx.x; i < nn; i += 256) out[i] = h[i];
}

// cnt[d] = sum over slices; dis[d] = rsqrt(cnt+1) fused.
__global__ void k_colsum(const int* __restrict__ bh, int* __restrict__ cnt,
                         float* __restrict__ dis, int n) {
    int d = blockIdx.x * blockDim.x + threadIdx.x;
    if (d >= n) return;
    const int nn = (n + NGROUPS - 1) / NGROUPS;
    int g = d / nn, ln = d - g * nn;
    int s = 0;
    for (int sl = 0; sl < NSLICES; sl++) s += bh[((size_t)(sl * NGROUPS + g)) * nn + ln];
    cnt[d] = s;
    dis[d] = rsqrtf((float)s + 1.0f);
}

// Hierarchical exclusive scan of cnt -> row_off
__global__ __launch_bounds__(256) void k_scan1(const int* __restrict__ cnt,
                                               int* __restrict__ loc,
                                               int* __restrict__ blk, int n) {
    __shared__ int s[256];
    int b = blockIdx.x, tid = threadIdx.x;
    int base = b * 1024 + tid * 4;
    int v0 = (base + 0 < n) ? cnt[base + 0] : 0;
    int v1 = (base + 1 < n) ? cnt[base + 1] : 0;
    int v2 = (base + 2 < n) ? cnt[base + 2] : 0;
    int v3 = (base + 3 < n) ? cnt[base + 3] : 0;
    int tsum = v0 + v1 + v2 + v3;
    s[tid] = tsum;
    __syncthreads();
    for (int off = 1; off < 256; off <<= 1) {
        int t = (tid >= off) ? s[tid - off] : 0;
        __syncthreads();
        s[tid] += t;
        __syncthreads();
    }
    int excl = s[tid] - tsum;
    if (base + 0 < n) loc[base + 0] = excl;
    if (base + 1 < n) loc[base + 1] = excl + v0;
    if (base + 2 < n) loc[base + 2] = excl + v0 + v1;
    if (base + 3 < n) loc[base + 3] = excl + v0 + v1 + v2;
    if (tid == 255) blk[b] = s[255];
}

__global__ __launch_bounds__(128) void k_scan2(int* __restrict__ blk, int nb,
                                               int* __restrict__ total_out) {
    __shared__ int s[128];
    int tid = threadIdx.x;
    int v = (tid < nb) ? blk[tid] : 0;
    s[tid] = v;
    __syncthreads();
    for (int off = 1; off < 128; off <<= 1) {
        int t = (tid >= off) ? s[tid - off] : 0;
        __syncthreads();
        s[tid] += t;
        __syncthreads();
    }
    if (tid < nb) blk[tid] = s[tid] - v;
    if (tid == 127) *total_out = s[127];
}

// Fused: row_off[i] += blk-offset, then per-node exclusive prefix across
// slices starting at row_off[i] (in-place over bh).
__global__ void k_scan3cb(int* __restrict__ row_off, const int* __restrict__ blk,
                          int* __restrict__ bh, int n) {
    int d = blockIdx.x * blockDim.x + threadIdx.x;
    if (d >= n) return;
    int ro = row_off[d] + blk[d >> 10];
    row_off[d] = ro;
    const int nn = (n + NGROUPS - 1) / NGROUPS;
    int g = d / nn, ln = d - g * nn;
    int running = ro;
    for (int sl = 0; sl < NSLICES; sl++) {
        size_t idx = ((size_t)(sl * NGROUPS + g)) * nn + ln;
        int t = bh[idx];
        bh[idx] = running;
        running += t;
    }
}

// Pass C: scatter {src, coef} via LDS cursors (no global atomics).
__global__ __launch_bounds__(256) void k_scatter(const int* __restrict__ src,
                                                 const int* __restrict__ dst,
                                                 const int* __restrict__ bh,
                                                 const float* __restrict__ dis,
                                                 int2* __restrict__ colcf, int n, int E) {
    __shared__ int cur[NN_MAX];
    const int b = blockIdx.x, g = b & (NGROUPS - 1);
    const int nn = (n + NGROUPS - 1) / NGROUPS;
    const int lo = g * nn;
    const int hi = min(n, lo + nn);
    const int* cb = bh + (size_t)b * nn;
    for (int i = threadIdx.x; i < hi - lo; i += 256) cur[i] = cb[i];
    __syncthreads();
    const int per = (((E + NSLICES - 1) / NSLICES) + 3) & ~3;   // mult of 4
    const int e0 = (b >> 4) * per, e1 = min(E, e0 + per);
    for (int base = e0 + threadIdx.x * 4; base < e1; base += 1024) {
        if (base + 4 <= e1) {
            int4 d4 = *(const int4*)(dst + base);
            int4 s4 = *(const int4*)(src + base);
            int dd[4] = {d4.x, d4.y, d4.z, d4.w};
            int ss[4] = {s4.x, s4.y, s4.z, s4.w};
#pragma unroll
            for (int j = 0; j < 4; j++) {
                int d = dd[j];
                if (d >= lo && d < hi) {
                    int s = ss[j];
                    int p = atomicAdd(&cur[d - lo], 1);
                    float cf = dis[s] * dis[d];
                    colcf[p] = make_int2(s, __float_as_int(cf));
                }
            }
        } else {
            for (int j = 0; j < 4; j++) {
                int ee = base + j;
                if (ee < e1) {
                    int d = dst[ee];
                    if (d >= lo && d < hi) {
                        int s = src[ee];
                        int p = atomicAdd(&cur[d - lo], 1);
                        float cf = dis[s] * dis[d];
                        colcf[p] = make_int2(s, __float_as_int(cf));
                    }
                }
            }
        }
    }
}

// Wt[layer][c][k] = bf16(W[layer][k][c])
__global__ void k_prepw(const float* __restrict__ Ws, __hip_bfloat16* __restrict__ Wt) {
    int i = blockIdx.x * blockDim.x + threadIdx.x;
    int layer = i >> 14;
    int r = (i >> 7) & 127;
    int c = i & 127;
    Wt[i] = __float2bfloat16(Ws[layer * 16384 + c * 128 + r]);
}

// H = X @ W via mfma_f32_16x16x32_bf16. 128 rows/block. B-fragments loaded
// per-lane DIRECTLY from global Wt (32 KB, L1-resident; no sW LDS tile ->
// 34.8 KB LDS, 4 blocks/CU). If Xf != null, stage fp32->bf16 (layer 0).
__global__ __launch_bounds__(256) void k_matmul(const __hip_bfloat16* __restrict__ Xb,
                                                const float* __restrict__ Xf,
                                                const __hip_bfloat16* __restrict__ Wt,
                                                __hip_bfloat16* __restrict__ Hb, int n) {
    __shared__ __align__(16) __hip_bfloat16 sX[128 * 136];
    const int tid = threadIdx.x;
    const int row0 = blockIdx.x * 128;
    if (Xf) {
        for (int i = tid; i < 4096; i += 256) {      // 128 rows x 32 float4
            int r = i >> 5, c = i & 31;
            int gr = row0 + r;
            float4 v = make_float4(0.f, 0.f, 0.f, 0.f);
            if (gr < n) v = *(const float4*)(Xf + (size_t)gr * 128 + c * 4);
            union { bf2 h2[2]; uint2 u; } pk;
            pk.h2[0].x = __float2bfloat16(v.x);
            pk.h2[0].y = __float2bfloat16(v.y);
            pk.h2[1].x = __float2bfloat16(v.z);
            pk.h2[1].y = __float2bfloat16(v.w);
            *(uint2*)(sX + r * 136 + c * 4) = pk.u;
        }
    } else {
        for (int i = tid; i < 2048; i += 256) {      // 128 rows x 16 uint4
            int r = i >> 4, ck = i & 15;
            uint4 v = make_uint4(0, 0, 0, 0);
            int gr = row0 + r;
            if (gr < n) v = *(const uint4*)(Xb + (size_t)gr * 128 + ck * 8);
            *(uint4*)(sX + r * 136 + ck * 8) = v;
        }
    }
    __syncthreads();
    const int w = tid >> 6, l = tid & 63;
    const int quad = l >> 4, lr = l & 15;
    f32x4 acc[2][8];
#pragma unroll
    for (int t = 0; t < 2; t++)
#pragma unroll
        for (int c = 0; c < 8; c++) acc[t][c] = (f32x4){0.f, 0.f, 0.f, 0.f};
    short8 a[2][4];
#pragma unroll
    for (int t = 0; t < 2; t++)
#pragma unroll
        for (int kb = 0; kb < 4; kb++)
            a[t][kb] = *(const short8*)(sX + (w * 32 + t * 16 + lr) * 136 + kb * 32 + quad * 8);
#pragma unroll
    for (int c = 0; c < 8; c++) {
#pragma unroll
        for (int kb = 0; kb < 4; kb++) {
            short8 b = *(const short8*)(Wt + (c * 16 + lr) * 128 + kb * 32 + quad * 8);
            acc[0][c] = __builtin_amdgcn_mfma_f32_16x16x32_bf16(a[0][kb], b, acc[0][c], 0, 0, 0);
            acc[1][c] = __builtin_amdgcn_mfma_f32_16x16x32_bf16(a[1][kb], b, acc[1][c], 0, 0, 0);
        }
    }
#pragma unroll
    for (int t = 0; t < 2; t++) {
#pragma unroll
        for (int c = 0; c < 8; c++)
#pragma unroll
            for (int r = 0; r < 4; r++)
                sX[(w * 32 + t * 16 + quad * 4 + r) * 136 + c * 16 + lr] =
                    __float2bfloat16(acc[t][c][r]);
#pragma unroll
        for (int p = 0; p < 4; p++) {
            int r = p * 4 + quad;
            int gr = row0 + w * 32 + t * 16 + r;
            uint4 v = *(const uint4*)(sX + (w * 32 + t * 16 + r) * 136 + lr * 8);
            if (gr < n) *(uint4*)(Hb + (size_t)gr * 128 + lr * 8) = v;
        }
    }
}

// 4 nodes per wave; 16-lane group per node, lane sub owns dims [sub*8,sub*8+8).
// Row load = dwordx4/lane; 8-edge batched gather (8 meta + 8 independent row
// loads in flight). Residual/output in bf16 (in-place on Xb). Intra-group LN.
__global__ __launch_bounds__(256) void k_node(const __hip_bfloat16* __restrict__ Hb,
                                              __hip_bfloat16* __restrict__ Xb,
                                              const int* __restrict__ row_off,
                                              const int2* __restrict__ colcf,
                                              const float* __restrict__ dis,
                                              const float* __restrict__ bias,
                                              const float* __restrict__ gamma,
                                              const float* __restrict__ beta,
                                              int do_relu, int do_res, int n) {
    const int wave = threadIdx.x >> 6;
    const int lane = threadIdx.x & 63;
    const int grp = lane >> 4;
    const int sub = lane & 15;
    const int node = blockIdx.x * 16 + wave * 4 + grp;
    const bool vn = node < n;
    const int e0 = vn ? row_off[node] : 0;
    const int e1 = vn ? row_off[node + 1] : 0;
    const char* hbase = (const char*)Hb;
    const unsigned suboff = (unsigned)(sub << 4);

    float acc[8];
#pragma unroll
    for (int k = 0; k < 8; k++) acc[k] = 0.f;

    int e = e0;
    while (__any(e < e1)) {
        int2 p[8];
        float cf[8];
#pragma unroll
        for (int u = 0; u < 8; u++) {
            int ee = e + u;
            bool ok = ee < e1;
            p[u] = colcf[ok ? ee : 0];
            cf[u] = ok ? __int_as_float(p[u].y) : 0.f;
        }
        uint4 v[8];
#pragma unroll
        for (int u = 0; u < 8; u++)
            v[u] = *(const uint4*)(hbase + (((unsigned)p[u].x) << 8) + suboff);
#pragma unroll
        for (int u = 0; u < 8; u++) {
            float c = cf[u];
            acc[0] += __uint_as_float(v[u].x << 16) * c;
            acc[1] += __uint_as_float(v[u].x & 0xffff0000u) * c;
            acc[2] += __uint_as_float(v[u].y << 16) * c;
            acc[3] += __uint_as_float(v[u].y & 0xffff0000u) * c;
            acc[4] += __uint_as_float(v[u].z << 16) * c;
            acc[5] += __uint_as_float(v[u].z & 0xffff0000u) * c;
            acc[6] += __uint_as_float(v[u].w << 16) * c;
            acc[7] += __uint_as_float(v[u].w & 0xffff0000u) * c;
        }
        e += 8;
    }

    // self-loop
    {
        int nd = vn ? node : 0;
        float dn = dis[nd];
        float dn2 = dn * dn;
        uint4 sv = *(const uint4*)(hbase + (((unsigned)nd) << 8) + suboff);
        acc[0] += __uint_as_float(sv.x << 16) * dn2;
        acc[1] += __uint_as_float(sv.x & 0xffff0000u) * dn2;
        acc[2] += __uint_as_float(sv.y << 16) * dn2;
        acc[3] += __uint_as_float(sv.y & 0xffff0000u) * dn2;
        acc[4] += __uint_as_float(sv.z << 16) * dn2;
        acc[5] += __uint_as_float(sv.z & 0xffff0000u) * dn2;
        acc[6] += __uint_as_float(sv.w << 16) * dn2;
        acc[7] += __uint_as_float(sv.w & 0xffff0000u) * dn2;
    }
    // bias
    float4 b0 = *(const float4*)(bias + sub * 8);
    float4 b1 = *(const float4*)(bias + sub * 8 + 4);
    acc[0] += b0.x; acc[1] += b0.y; acc[2] += b0.z; acc[3] += b0.w;
    acc[4] += b1.x; acc[5] += b1.y; acc[6] += b1.z; acc[7] += b1.w;

    // LayerNorm within the 16-lane group
    float s = acc[0] + acc[1] + acc[2] + acc[3] + acc[4] + acc[5] + acc[6] + acc[7];
#pragma unroll
    for (int m = 8; m > 0; m >>= 1) s += __shfl_xor(s, m, 64);
    float mu = s * (1.f / 128.f);
    float vs = 0.f;
#pragma unroll
    for (int k = 0; k < 8; k++) {
        float d = acc[k] - mu;
        acc[k] = d;
        vs += d * d;
    }
#pragma unroll
    for (int m = 8; m > 0; m >>= 1) vs += __shfl_xor(vs, m, 64);
    float rs = rsqrtf(vs * (1.f / 128.f) + 1e-5f);

    float4 g0 = *(const float4*)(gamma + sub * 8);
    float4 g1 = *(const float4*)(gamma + sub * 8 + 4);
    float4 t0 = *(const float4*)(beta + sub * 8);
    float4 t1 = *(const float4*)(beta + sub * 8 + 4);
    float y[8];
    y[0] = acc[0] * rs * g0.x + t0.x;
    y[1] = acc[1] * rs * g0.y + t0.y;
    y[2] = acc[2] * rs * g0.z + t0.z;
    y[3] = acc[3] * rs * g0.w + t0.w;
    y[4] = acc[4] * rs * g1.x + t1.x;
    y[5] = acc[5] * rs * g1.y + t1.y;
    y[6] = acc[6] * rs * g1.z + t1.z;
    y[7] = acc[7] * rs * g1.w + t1.w;

    if (vn) {
        __hip_bfloat16* xp = Xb + (size_t)node * 128 + sub * 8;
        if (do_res) {
            uint4 rv = *(const uint4*)xp;
            y[0] += __uint_as_float(rv.x << 16);
            y[1] += __uint_as_float(rv.x & 0xffff0000u);
            y[2] += __uint_as_float(rv.y << 16);
            y[3] += __uint_as_float(rv.y & 0xffff0000u);
            y[4] += __uint_as_float(rv.z << 16);
            y[5] += __uint_as_float(rv.z & 0xffff0000u);
            y[6] += __uint_as_float(rv.w << 16);
            y[7] += __uint_as_float(rv.w & 0xffff0000u);
        }
        if (do_relu) {
#pragma unroll
            for (int k = 0; k < 8; k++) y[k] = fmaxf(y[k], 0.f);
        }
        union { bf2 h2[4]; uint4 u; } pk;
        pk.h2[0].x = __float2bfloat16(y[0]); pk.h2[0].y = __float2bfloat16(y[1]);
        pk.h2[1].x = __float2bfloat16(y[2]); pk.h2[1].y = __float2bfloat16(y[3]);
        pk.h2[2].x = __float2bfloat16(y[4]); pk.h2[2].y = __float2bfloat16(y[5]);
        pk.h2[3].x = __float2bfloat16(y[6]); pk.h2[3].y = __float2bfloat16(y[7]);
        *(uint4*)xp = pk.u;
    }
}

// One 128-thread block per graph: binary-search segment, bf16 rows, fp32 acc.
__global__ __launch_bounds__(128) void k_pool(const __hip_bfloat16* __restrict__ X,
                                              const int* __restrict__ batch,
                                              const float* __restrict__ lin_w,
                                              const float* __restrict__ lin_b,
                                              float* __restrict__ out, int n) {
    int g = blockIdx.x;
    int d = threadIdx.x;
    int lo = 0, hi = n;
    while (lo < hi) { int m = (lo + hi) >> 1; if (batch[m] < g) lo = m + 1; else hi = m; }
    int start = lo;
    hi = n;
    while (lo < hi) { int m = (lo + hi) >> 1; if (batch[m] <= g) lo = m + 1; else hi = m; }
    int end = lo;
    float s = 0.f;
    for (int i = start; i < end; i++)
        s += __bfloat162float(X[(size_t)i * 128 + d]);
    float cntf = (float)(end - start);
    float mean = s / fmaxf(cntf, 1.f);
    float p = mean * lin_w[d];
    __shared__ float red[2];
#pragma unroll
    for (int off = 32; off > 0; off >>= 1) p += __shfl_down(p, off, 64);
    if ((d & 63) == 0) red[d >> 6] = p;
    __syncthreads();
    if (d == 0) out[g] = red[0] + red[1] + lin_b[0];
}

extern "C" void kernel_launch(void* const* d_in, const int* in_sizes, int n_in,
                              void* d_out, int out_size, void* d_ws, size_t ws_size,
                              hipStream_t stream) {
    const float* x      = (const float*)d_in[0];
    const int*   eidx   = (const int*)d_in[1];
    const int*   batch  = (const int*)d_in[2];
    const float* Ws     = (const float*)d_in[3];
    const float* bs     = (const float*)d_in[4];
    const float* gammas = (const float*)d_in[5];
    const float* betas  = (const float*)d_in[6];
    const float* lin_w  = (const float*)d_in[7];
    const float* lin_b  = (const float*)d_in[8];
    float* out = (float*)d_out;

    const int n = in_sizes[2];        // 100000
    const int E = in_sizes[1] / 2;    // 1600000
    const int G = out_size;           // 512
    const int nb = (n + 1023) / 1024;

    const int* src  = eidx;
    const int* dstp = eidx + E;

    char* w = (char*)d_ws;
    size_t off = 0;
    auto alloc = [&](size_t bytes) {
        void* p = w + off;
        off = (off + bytes + 15) & ~(size_t)15;
        return p;
    };
    int*   cnt     = (int*)  alloc((size_t)n * 4);
    int*   row_off = (int*)  alloc((size_t)(n + 1) * 4);
    int*   blk     = (int*)  alloc(128 * 4);
    float* dis     = (float*)alloc((size_t)n * 4);
    int2*  colcf   = (int2*) alloc((size_t)E * 8);
    __hip_bfloat16* hb  = (__hip_bfloat16*)alloc((size_t)n * 128 * 2);
    __hip_bfloat16* xb  = (__hip_bfloat16*)alloc((size_t)n * 128 * 2);
    __hip_bfloat16* wt  = (__hip_bfloat16*)alloc((size_t)4 * 128 * 128 * 2);
    // bh aliases hb+xb (contiguous, 51.2 MB total; both first written AFTER
    // k_scatter consumes bh: hb at matmul layer-0, xb at k_node layer-0).
    int* bh = (int*)hb;
    (void)ws_size; (void)n_in;

    k_bhist<<<NSLICES * NGROUPS, 256, 0, stream>>>(dstp, bh, n, E);
    k_colsum<<<(n + 255) / 256, 256, 0, stream>>>(bh, cnt, dis, n);
    k_scan1<<<nb, 256, 0, stream>>>(cnt, row_off, blk, n);
    k_scan2<<<1, 128, 0, stream>>>(blk, nb, row_off + n);
    k_scan3cb<<<(n + 255) / 256, 256, 0, stream>>>(row_off, blk, bh, n);
    k_scatter<<<NSLICES * NGROUPS, 256, 0, stream>>>(src, dstp, bh, dis, colcf, n, E);
    k_prepw<<<(4 * 128 * 128 + 255) / 256, 256, 0, stream>>>(Ws, wt);

    for (int layer = 0; layer < 4; layer++) {
        k_matmul<<<(n + 127) / 128, 256, 0, stream>>>(xb, (layer == 0) ? x : nullptr,
                                                      wt + (size_t)layer * 16384, hb, n);
        k_node<<<(n + 15) / 16, 256, 0, stream>>>(hb, xb, row_off, colcf, dis,
                                                  bs + (size_t)layer * 128,
                                                  gammas + (size_t)layer * 128,
                                                  betas + (size_t)layer * 128,
                                                  (layer < 3) ? 1 : 0, (layer > 0) ? 1 : 0, n);
    }
    k_pool<<<G, 128, 0, stream>>>(xb, batch, lin_w, lin_b, out, n);
}

// Round 17
// 704.297 us; speedup vs baseline: 1.0410x; 1.0410x over previous
//
#include <hip/hip_runtime.h>
#include <hip/hip_bf16.h>

// ---------------------------------------------------------------------------
// MatGCN: 4-layer GCN (D=128) + LN + residual + mean-pool + linear head.
// R16 (resubmit; prior bench lost to container-level infra failure — same
// signature as R9/R13, both passed unchanged on retry): Wt pre-packed in MFMA
// B-fragment order -> k_matmul B-loads are fully coalesced 1KB/wave global
// loads (fixes R13's 16-line-scatter regression while keeping no-sW /
// 34.8 KB LDS / 4 blocks/CU). k_node 8-wide kept. Build unchanged from R12.
// ---------------------------------------------------------------------------

typedef __hip_bfloat162 bf2;
typedef __attribute__((ext_vector_type(8))) short short8;
typedef __attribute__((ext_vector_type(4))) float f32x4;

#define NGROUPS 16          // node-range groups (nn = ceil(n/16) = 6250)
#define NSLICES 128         // edge slices; grid = NSLICES*NGROUPS = 2048
#define NN_MAX 6400         // >= ceil(100000/16); 25.6 KB LDS

// Pass A: per-(slice,group) node histogram. LDS atomics only; int4 dst loads.
__global__ __launch_bounds__(256) void k_bhist(const int* __restrict__ dst,
                                               int* __restrict__ bh, int n, int E) {
    __shared__ int h[NN_MAX];
    const int b = blockIdx.x, g = b & (NGROUPS - 1);
    const int nn = (n + NGROUPS - 1) / NGROUPS;
    const int lo = g * nn;
    const int hi = min(n, lo + nn);
    for (int i = threadIdx.x; i < nn; i += 256) h[i] = 0;
    __syncthreads();
    const int per = (((E + NSLICES - 1) / NSLICES) + 3) & ~3;   // mult of 4
    const int e0 = (b >> 4) * per, e1 = min(E, e0 + per);
    for (int base = e0 + threadIdx.x * 4; base < e1; base += 1024) {
        if (base + 4 <= e1) {
            int4 d4 = *(const int4*)(dst + base);
            if (d4.x >= lo && d4.x < hi) atomicAdd(&h[d4.x - lo], 1);
            if (d4.y >= lo && d4.y < hi) atomicAdd(&h[d4.y - lo], 1);
            if (d4.z >= lo && d4.z < hi) atomicAdd(&h[d4.z - lo], 1);
            if (d4.w >= lo && d4.w < hi) atomicAdd(&h[d4.w - lo], 1);
        } else {
            for (int j = 0; j < 4; j++) {
                int ee = base + j;
                if (ee < e1) {
                    int d = dst[ee];
                    if (d >= lo && d < hi) atomicAdd(&h[d - lo], 1);
                }
            }
        }
    }
    __syncthreads();
    int* out = bh + (size_t)b * nn;
    for (int i = threadIdx.x; i < nn; i += 256) out[i] = h[i];
}

// cnt[d] = sum over slices; dis[d] = rsqrt(cnt+1) fused.
__global__ void k_colsum(const int* __restrict__ bh, int* __restrict__ cnt,
                         float* __restrict__ dis, int n) {
    int d = blockIdx.x * blockDim.x + threadIdx.x;
    if (d >= n) return;
    const int nn = (n + NGROUPS - 1) / NGROUPS;
    int g = d / nn, ln = d - g * nn;
    int s = 0;
    for (int sl = 0; sl < NSLICES; sl++) s += bh[((size_t)(sl * NGROUPS + g)) * nn + ln];
    cnt[d] = s;
    dis[d] = rsqrtf((float)s + 1.0f);
}

// Hierarchical exclusive scan of cnt -> row_off
__global__ __launch_bounds__(256) void k_scan1(const int* __restrict__ cnt,
                                               int* __restrict__ loc,
                                               int* __restrict__ blk, int n) {
    __shared__ int s[256];
    int b = blockIdx.x, tid = threadIdx.x;
    int base = b * 1024 + tid * 4;
    int v0 = (base + 0 < n) ? cnt[base + 0] : 0;
    int v1 = (base + 1 < n) ? cnt[base + 1] : 0;
    int v2 = (base + 2 < n) ? cnt[base + 2] : 0;
    int v3 = (base + 3 < n) ? cnt[base + 3] : 0;
    int tsum = v0 + v1 + v2 + v3;
    s[tid] = tsum;
    __syncthreads();
    for (int off = 1; off < 256; off <<= 1) {
        int t = (tid >= off) ? s[tid - off] : 0;
        __syncthreads();
        s[tid] += t;
        __syncthreads();
    }
    int excl = s[tid] - tsum;
    if (base + 0 < n) loc[base + 0] = excl;
    if (base + 1 < n) loc[base + 1] = excl + v0;
    if (base + 2 < n) loc[base + 2] = excl + v0 + v1;
    if (base + 3 < n) loc[base + 3] = excl + v0 + v1 + v2;
    if (tid == 255) blk[b] = s[255];
}

__global__ __launch_bounds__(128) void k_scan2(int* __restrict__ blk, int nb,
                                               int* __restrict__ total_out) {
    __shared__ int s[128];
    int tid = threadIdx.x;
    int v = (tid < nb) ? blk[tid] : 0;
    s[tid] = v;
    __syncthreads();
    for (int off = 1; off < 128; off <<= 1) {
        int t = (tid >= off) ? s[tid - off] : 0;
        __syncthreads();
        s[tid] += t;
        __syncthreads();
    }
    if (tid < nb) blk[tid] = s[tid] - v;
    if (tid == 127) *total_out = s[127];
}

// Fused: row_off[i] += blk-offset, then per-node exclusive prefix across
// slices starting at row_off[i] (in-place over bh).
__global__ void k_scan3cb(int* __restrict__ row_off, const int* __restrict__ blk,
                          int* __restrict__ bh, int n) {
    int d = blockIdx.x * blockDim.x + threadIdx.x;
    if (d >= n) return;
    int ro = row_off[d] + blk[d >> 10];
    row_off[d] = ro;
    const int nn = (n + NGROUPS - 1) / NGROUPS;
    int g = d / nn, ln = d - g * nn;
    int running = ro;
    for (int sl = 0; sl < NSLICES; sl++) {
        size_t idx = ((size_t)(sl * NGROUPS + g)) * nn + ln;
        int t = bh[idx];
        bh[idx] = running;
        running += t;
    }
}

// Pass C: scatter {src, coef} via LDS cursors (no global atomics).
__global__ __launch_bounds__(256) void k_scatter(const int* __restrict__ src,
                                                 const int* __restrict__ dst,
                                                 const int* __restrict__ bh,
                                                 const float* __restrict__ dis,
                                                 int2* __restrict__ colcf, int n, int E) {
    __shared__ int cur[NN_MAX];
    const int b = blockIdx.x, g = b & (NGROUPS - 1);
    const int nn = (n + NGROUPS - 1) / NGROUPS;
    const int lo = g * nn;
    const int hi = min(n, lo + nn);
    const int* cb = bh + (size_t)b * nn;
    for (int i = threadIdx.x; i < hi - lo; i += 256) cur[i] = cb[i];
    __syncthreads();
    const int per = (((E + NSLICES - 1) / NSLICES) + 3) & ~3;   // mult of 4
    const int e0 = (b >> 4) * per, e1 = min(E, e0 + per);
    for (int base = e0 + threadIdx.x * 4; base < e1; base += 1024) {
        if (base + 4 <= e1) {
            int4 d4 = *(const int4*)(dst + base);
            int4 s4 = *(const int4*)(src + base);
            int dd[4] = {d4.x, d4.y, d4.z, d4.w};
            int ss[4] = {s4.x, s4.y, s4.z, s4.w};
#pragma unroll
            for (int j = 0; j < 4; j++) {
                int d = dd[j];
                if (d >= lo && d < hi) {
                    int s = ss[j];
                    int p = atomicAdd(&cur[d - lo], 1);
                    float cf = dis[s] * dis[d];
                    colcf[p] = make_int2(s, __float_as_int(cf));
                }
            }
        } else {
            for (int j = 0; j < 4; j++) {
                int ee = base + j;
                if (ee < e1) {
                    int d = dst[ee];
                    if (d >= lo && d < hi) {
                        int s = src[ee];
                        int p = atomicAdd(&cur[d - lo], 1);
                        float cf = dis[s] * dis[d];
                        colcf[p] = make_int2(s, __float_as_int(cf));
                    }
                }
            }
        }
    }
}

// Wt packed in MFMA B-fragment order:
// Wt[layer][((c*4+kb)*64 + lane)*8 + j] = bf16(W[layer][kb*32+(lane>>4)*8+j][c*16+(lane&15)])
// -> per (c,kb) fragment, lane l reads 16 contiguous bytes at (c*4+kb)*1024 + l*16.
__global__ void k_prepw(const float* __restrict__ Ws, __hip_bfloat16* __restrict__ Wt) {
    int i = blockIdx.x * blockDim.x + threadIdx.x;   // 4*16384
    int layer = i >> 14;
    int m = i & 16383;
    int j = m & 7;
    int l = (m >> 3) & 63;
    int ckb = m >> 9;            // [0,32)
    int kb = ckb & 3;
    int c = ckb >> 2;            // [0,8)
    int quad = l >> 4, lr = l & 15;
    int k = kb * 32 + quad * 8 + j;      // [0,128)
    int col = c * 16 + lr;               // [0,128)
    Wt[i] = __float2bfloat16(Ws[layer * 16384 + k * 128 + col]);
}

// H = X @ W via mfma_f32_16x16x32_bf16. 128 rows/block. B-fragments loaded
// per-lane from fragment-ordered Wt: one coalesced 1KB load per (c,kb) per
// wave. No sW LDS tile -> 34.8 KB LDS, 4 blocks/CU. Xf != null: layer 0.
__global__ __launch_bounds__(256) void k_matmul(const __hip_bfloat16* __restrict__ Xb,
                                                const float* __restrict__ Xf,
                                                const __hip_bfloat16* __restrict__ Wt,
                                                __hip_bfloat16* __restrict__ Hb, int n) {
    __shared__ __align__(16) __hip_bfloat16 sX[128 * 136];
    const int tid = threadIdx.x;
    const int row0 = blockIdx.x * 128;
    if (Xf) {
        for (int i = tid; i < 4096; i += 256) {      // 128 rows x 32 float4
            int r = i >> 5, c = i & 31;
            int gr = row0 + r;
            float4 v = make_float4(0.f, 0.f, 0.f, 0.f);
            if (gr < n) v = *(const float4*)(Xf + (size_t)gr * 128 + c * 4);
            union { bf2 h2[2]; uint2 u; } pk;
            pk.h2[0].x = __float2bfloat16(v.x);
            pk.h2[0].y = __float2bfloat16(v.y);
            pk.h2[1].x = __float2bfloat16(v.z);
            pk.h2[1].y = __float2bfloat16(v.w);
            *(uint2*)(sX + r * 136 + c * 4) = pk.u;
        }
    } else {
        for (int i = tid; i < 2048; i += 256) {      // 128 rows x 16 uint4
            int r = i >> 4, ck = i & 15;
            uint4 v = make_uint4(0, 0, 0, 0);
            int gr = row0 + r;
            if (gr < n) v = *(const uint4*)(Xb + (size_t)gr * 128 + ck * 8);
            *(uint4*)(sX + r * 136 + ck * 8) = v;
        }
    }
    __syncthreads();
    const int w = tid >> 6, l = tid & 63;
    const int quad = l >> 4, lr = l & 15;
    f32x4 acc[2][8];
#pragma unroll
    for (int t = 0; t < 2; t++)
#pragma unroll
        for (int c = 0; c < 8; c++) acc[t][c] = (f32x4){0.f, 0.f, 0.f, 0.f};
    short8 a[2][4];
#pragma unroll
    for (int t = 0; t < 2; t++)
#pragma unroll
        for (int kb = 0; kb < 4; kb++)
            a[t][kb] = *(const short8*)(sX + (w * 32 + t * 16 + lr) * 136 + kb * 32 + quad * 8);
#pragma unroll
    for (int c = 0; c < 8; c++) {
#pragma unroll
        for (int kb = 0; kb < 4; kb++) {
            short8 b = *(const short8*)(Wt + ((c * 4 + kb) * 64 + l) * 8);
            acc[0][c] = __builtin_amdgcn_mfma_f32_16x16x32_bf16(a[0][kb], b, acc[0][c], 0, 0, 0);
            acc[1][c] = __builtin_amdgcn_mfma_f32_16x16x32_bf16(a[1][kb], b, acc[1][c], 0, 0, 0);
        }
    }
#pragma unroll
    for (int t = 0; t < 2; t++) {
#pragma unroll
        for (int c = 0; c < 8; c++)
#pragma unroll
            for (int r = 0; r < 4; r++)
                sX[(w * 32 + t * 16 + quad * 4 + r) * 136 + c * 16 + lr] =
                    __float2bfloat16(acc[t][c][r]);
#pragma unroll
        for (int p = 0; p < 4; p++) {
            int r = p * 4 + quad;
            int gr = row0 + w * 32 + t * 16 + r;
            uint4 v = *(const uint4*)(sX + (w * 32 + t * 16 + r) * 136 + lr * 8);
            if (gr < n) *(uint4*)(Hb + (size_t)gr * 128 + lr * 8) = v;
        }
    }
}

// 4 nodes per wave; 16-lane group per node, lane sub owns dims [sub*8,sub*8+8).
// Row load = dwordx4/lane; 8-edge batched gather. Residual/output in bf16
// (in-place on Xb). Intra-group LN.
__global__ __launch_bounds__(256) void k_node(const __hip_bfloat16* __restrict__ Hb,
                                              __hip_bfloat16* __restrict__ Xb,
                                              const int* __restrict__ row_off,
                                              const int2* __restrict__ colcf,
                                              const float* __restrict__ dis,
                                              const float* __restrict__ bias,
                                              const float* __restrict__ gamma,
                                              const float* __restrict__ beta,
                                              int do_relu, int do_res, int n) {
    const int wave = threadIdx.x >> 6;
    const int lane = threadIdx.x & 63;
    const int grp = lane >> 4;
    const int sub = lane & 15;
    const int node = blockIdx.x * 16 + wave * 4 + grp;
    const bool vn = node < n;
    const int e0 = vn ? row_off[node] : 0;
    const int e1 = vn ? row_off[node + 1] : 0;
    const char* hbase = (const char*)Hb;
    const unsigned suboff = (unsigned)(sub << 4);

    float acc[8];
#pragma unroll
    for (int k = 0; k < 8; k++) acc[k] = 0.f;

    int e = e0;
    while (__any(e < e1)) {
        int2 p[8];
        float cf[8];
#pragma unroll
        for (int u = 0; u < 8; u++) {
            int ee = e + u;
            bool ok = ee < e1;
            p[u] = colcf[ok ? ee : 0];
            cf[u] = ok ? __int_as_float(p[u].y) : 0.f;
        }
        uint4 v[8];
#pragma unroll
        for (int u = 0; u < 8; u++)
            v[u] = *(const uint4*)(hbase + (((unsigned)p[u].x) << 8) + suboff);
#pragma unroll
        for (int u = 0; u < 8; u++) {
            float c = cf[u];
            acc[0] += __uint_as_float(v[u].x << 16) * c;
            acc[1] += __uint_as_float(v[u].x & 0xffff0000u) * c;
            acc[2] += __uint_as_float(v[u].y << 16) * c;
            acc[3] += __uint_as_float(v[u].y & 0xffff0000u) * c;
            acc[4] += __uint_as_float(v[u].z << 16) * c;
            acc[5] += __uint_as_float(v[u].z & 0xffff0000u) * c;
            acc[6] += __uint_as_float(v[u].w << 16) * c;
            acc[7] += __uint_as_float(v[u].w & 0xffff0000u) * c;
        }
        e += 8;
    }

    // self-loop
    {
        int nd = vn ? node : 0;
        float dn = dis[nd];
        float dn2 = dn * dn;
        uint4 sv = *(const uint4*)(hbase + (((unsigned)nd) << 8) + suboff);
        acc[0] += __uint_as_float(sv.x << 16) * dn2;
        acc[1] += __uint_as_float(sv.x & 0xffff0000u) * dn2;
        acc[2] += __uint_as_float(sv.y << 16) * dn2;
        acc[3] += __uint_as_float(sv.y & 0xffff0000u) * dn2;
        acc[4] += __uint_as_float(sv.z << 16) * dn2;
        acc[5] += __uint_as_float(sv.z & 0xffff0000u) * dn2;
        acc[6] += __uint_as_float(sv.w << 16) * dn2;
        acc[7] += __uint_as_float(sv.w & 0xffff0000u) * dn2;
    }
    // bias
    float4 b0 = *(const float4*)(bias + sub * 8);
    float4 b1 = *(const float4*)(bias + sub * 8 + 4);
    acc[0] += b0.x; acc[1] += b0.y; acc[2] += b0.z; acc[3] += b0.w;
    acc[4] += b1.x; acc[5] += b1.y; acc[6] += b1.z; acc[7] += b1.w;

    // LayerNorm within the 16-lane group
    float s = acc[0] + acc[1] + acc[2] + acc[3] + acc[4] + acc[5] + acc[6] + acc[7];
#pragma unroll
    for (int m = 8; m > 0; m >>= 1) s += __shfl_xor(s, m, 64);
    float mu = s * (1.f / 128.f);
    float vs = 0.f;
#pragma unroll
    for (int k = 0; k < 8; k++) {
        float d = acc[k] - mu;
        acc[k] = d;
        vs += d * d;
    }
#pragma unroll
    for (int m = 8; m > 0; m >>= 1) vs += __shfl_xor(vs, m, 64);
    float rs = rsqrtf(vs * (1.f / 128.f) + 1e-5f);

    float4 g0 = *(const float4*)(gamma + sub * 8);
    float4 g1 = *(const float4*)(gamma + sub * 8 + 4);
    float4 t0 = *(const float4*)(beta + sub * 8);
    float4 t1 = *(const float4*)(beta + sub * 8 + 4);
    float y[8];
    y[0] = acc[0] * rs * g0.x + t0.x;
    y[1] = acc[1] * rs * g0.y + t0.y;
    y[2] = acc[2] * rs * g0.z + t0.z;
    y[3] = acc[3] * rs * g0.w + t0.w;
    y[4] = acc[4] * rs * g1.x + t1.x;
    y[5] = acc[5] * rs * g1.y + t1.y;
    y[6] = acc[6] * rs * g1.z + t1.z;
    y[7] = acc[7] * rs * g1.w + t1.w;

    if (vn) {
        __hip_bfloat16* xp = Xb + (size_t)node * 128 + sub * 8;
        if (do_res) {
            uint4 rv = *(const uint4*)xp;
            y[0] += __uint_as_float(rv.x << 16);
            y[1] += __uint_as_float(rv.x & 0xffff0000u);
            y[2] += __uint_as_float(rv.y << 16);
            y[3] += __uint_as_float(rv.y & 0xffff0000u);
            y[4] += __uint_as_float(rv.z << 16);
            y[5] += __uint_as_float(rv.z & 0xffff0000u);
            y[6] += __uint_as_float(rv.w << 16);
            y[7] += __uint_as_float(rv.w & 0xffff0000u);
        }
        if (do_relu) {
#pragma unroll
            for (int k = 0; k < 8; k++) y[k] = fmaxf(y[k], 0.f);
        }
        union { bf2 h2[4]; uint4 u; } pk;
        pk.h2[0].x = __float2bfloat16(y[0]); pk.h2[0].y = __float2bfloat16(y[1]);
        pk.h2[1].x = __float2bfloat16(y[2]); pk.h2[1].y = __float2bfloat16(y[3]);
        pk.h2[2].x = __float2bfloat16(y[4]); pk.h2[2].y = __float2bfloat16(y[5]);
        pk.h2[3].x = __float2bfloat16(y[6]); pk.h2[3].y = __float2bfloat16(y[7]);
        *(uint4*)xp = pk.u;
    }
}

// One 128-thread block per graph: binary-search segment, bf16 rows, fp32 acc.
__global__ __launch_bounds__(128) void k_pool(const __hip_bfloat16* __restrict__ X,
                                              const int* __restrict__ batch,
                                              const float* __restrict__ lin_w,
                                              const float* __restrict__ lin_b,
                                              float* __restrict__ out, int n) {
    int g = blockIdx.x;
    int d = threadIdx.x;
    int lo = 0, hi = n;
    while (lo < hi) { int m = (lo + hi) >> 1; if (batch[m] < g) lo = m + 1; else hi = m; }
    int start = lo;
    hi = n;
    while (lo < hi) { int m = (lo + hi) >> 1; if (batch[m] <= g) lo = m + 1; else hi = m; }
    int end = lo;
    float s = 0.f;
    for (int i = start; i < end; i++)
        s += __bfloat162float(X[(size_t)i * 128 + d]);
    float cntf = (float)(end - start);
    float mean = s / fmaxf(cntf, 1.f);
    float p = mean * lin_w[d];
    __shared__ float red[2];
#pragma unroll
    for (int off = 32; off > 0; off >>= 1) p += __shfl_down(p, off, 64);
    if ((d & 63) == 0) red[d >> 6] = p;
    __syncthreads();
    if (d == 0) out[g] = red[0] + red[1] + lin_b[0];
}

extern "C" void kernel_launch(void* const* d_in, const int* in_sizes, int n_in,
                              void* d_out, int out_size, void* d_ws, size_t ws_size,
                              hipStream_t stream) {
    const float* x      = (const float*)d_in[0];
    const int*   eidx   = (const int*)d_in[1];
    const int*   batch  = (const int*)d_in[2];
    const float* Ws     = (const float*)d_in[3];
    const float* bs     = (const float*)d_in[4];
    const float* gammas = (const float*)d_in[5];
    const float* betas  = (const float*)d_in[6];
    const float* lin_w  = (const float*)d_in[7];
    const float* lin_b  = (const float*)d_in[8];
    float* out = (float*)d_out;

    const int n = in_sizes[2];        // 100000
    const int E = in_sizes[1] / 2;    // 1600000
    const int G = out_size;           // 512
    const int nb = (n + 1023) / 1024;

    const int* src  = eidx;
    const int* dstp = eidx + E;

    char* w = (char*)d_ws;
    size_t off = 0;
    auto alloc = [&](size_t bytes) {
        void* p = w + off;
        off = (off + bytes + 15) & ~(size_t)15;
        return p;
    };
    int*   cnt     = (int*)  alloc((size_t)n * 4);
    int*   row_off = (int*)  alloc((size_t)(n + 1) * 4);
    int*   blk     = (int*)  alloc(128 * 4);
    float* dis     = (float*)alloc((size_t)n * 4);
    int2*  colcf   = (int2*) alloc((size_t)E * 8);
    __hip_bfloat16* hb  = (__hip_bfloat16*)alloc((size_t)n * 128 * 2);
    __hip_bfloat16* xb  = (__hip_bfloat16*)alloc((size_t)n * 128 * 2);
    __hip_bfloat16* wt  = (__hip_bfloat16*)alloc((size_t)4 * 128 * 128 * 2);
    // bh aliases hb+xb (contiguous, 51.2 MB total; both first written AFTER
    // k_scatter consumes bh: hb at matmul layer-0, xb at k_node layer-0).
    int* bh = (int*)hb;
    (void)ws_size; (void)n_in;

    k_bhist<<<NSLICES * NGROUPS, 256, 0, stream>>>(dstp, bh, n, E);
    k_colsum<<<(n + 255) / 256, 256, 0, stream>>>(bh, cnt, dis, n);
    k_scan1<<<nb, 256, 0, stream>>>(cnt, row_off, blk, n);
    k_scan2<<<1, 128, 0, stream>>>(blk, nb, row_off + n);
    k_scan3cb<<<(n + 255) / 256, 256, 0, stream>>>(row_off, blk, bh, n);
    k_scatter<<<NSLICES * NGROUPS, 256, 0, stream>>>(src, dstp, bh, dis, colcf, n, E);
    k_prepw<<<(4 * 128 * 128 + 255) / 256, 256, 0, stream>>>(Ws, wt);

    for (int layer = 0; layer < 4; layer++) {
        k_matmul<<<(n + 127) / 128, 256, 0, stream>>>(xb, (layer == 0) ? x : nullptr,
                                                      wt + (size_t)layer * 16384, hb, n);
        k_node<<<(n + 15) / 16, 256, 0, stream>>>(hb, xb, row_off, colcf, dis,
                                                  bs + (size_t)layer * 128,
                                                  gammas + (size_t)layer * 128,
                                                  betas + (size_t)layer * 128,
                                                  (layer < 3) ? 1 : 0, (layer > 0) ? 1 : 0, n);
    }
    k_pool<<<G, 128, 0, stream>>>(xb, batch, lin_w, lin_b, out, n);
}